// Round 1
// baseline (2305.199 us; speedup 1.0000x reference)
//
#include <hip/hip_runtime.h>
#include <math.h>

#define D 64
#define MIN_NORM 1e-15f

// ---------------- wave helpers (wave64, lane = dim) ----------------

__device__ __forceinline__ float wave_sum(float v) {
    v += __shfl_xor(v, 1, 64);
    v += __shfl_xor(v, 2, 64);
    v += __shfl_xor(v, 4, 64);
    v += __shfl_xor(v, 8, 64);
    v += __shfl_xor(v, 16, 64);
    v += __shfl_xor(v, 32, 64);
    return v;
}

// mobius_add on per-lane components x,y (each lane holds one of the 64 dims)
__device__ __forceinline__ float mobius_add_lane(float x, float y) {
    float X2 = wave_sum(x * x);
    float Y2 = wave_sum(y * y);
    float XY = wave_sum(x * y);
    float num = (1.0f + 2.0f * XY + Y2) * x + (1.0f - X2) * y;
    float den = 1.0f + 2.0f * XY + X2 * Y2;
    return num / fmaxf(den, MIN_NORM);
}

// ---------------- RGAT edge kernel: one wave per edge ----------------

__global__ __launch_bounds__(256) void rgat_edge_kernel(
    const float* __restrict__ ent, const float* __restrict__ rel,
    const int* __restrict__ head, const int* __restrict__ tail,
    const int* __restrict__ etype,
    float* __restrict__ sums, float* __restrict__ cnt, int n_edges)
{
    int e = blockIdx.x * 4 + (threadIdx.x >> 6);
    if (e >= n_edges) return;
    int lane = threadIdx.x & 63;

    int h = head[e];
    int t = tail[e];
    int r = etype[e] - 1;

    float he = ent[(size_t)h * D + lane];
    float te = ent[(size_t)t * D + lane];
    float re = rel[(size_t)r * D + lane];

    // ricci = l2norm(te + re), eps 1e-12
    float s = te + re;
    float S2 = wave_sum(s * s);
    float ricci = s / fmaxf(sqrtf(S2), 1e-12f);

    // hh = expmap0(he) = tanh(||he||) * he / ||he||
    float HE2 = wave_sum(he * he);
    float Nhe = fmaxf(sqrtf(HE2), MIN_NORM);
    float hh = tanhf(Nhe) * he / Nhe;

    // lam = 2 / max(1 - ||hh||^2, MIN_NORM)
    float HH2 = wave_sum(hh * hh);
    float lam = 2.0f / fmaxf(1.0f - HH2, MIN_NORM);

    // ht = expmap(te, hh) = mobius_add(hh, tanh(0.5*lam*||te||) * te/||te||)
    float TE2 = wave_sum(te * te);
    float Nte = fmaxf(sqrtf(TE2), MIN_NORM);
    float wt = tanhf(0.5f * lam * Nte) * te / Nte;
    float ht = mobius_add_lane(hh, wt);

    // hr = expmap(re, hh)
    float RE2 = wave_sum(re * re);
    float Nre = fmaxf(sqrtf(RE2), MIN_NORM);
    float wr = tanhf(0.5f * lam * Nre) * re / Nre;
    float hr = mobius_add_lane(hh, wr);

    // res = project(mobius_add(ht, hr))
    float res = mobius_add_lane(ht, hr);
    float R2 = wave_sum(res * res);
    float Nr = fmaxf(sqrtf(R2), MIN_NORM);
    const float maxn = 1.0f - 1e-3f;
    if (Nr > maxn) res = res / Nr * maxn;   // wave-uniform branch

    // logmap(res, hh): sub = mobius_add(-hh, res)
    float sub = mobius_add_lane(-hh, res);
    float SUB2 = wave_sum(sub * sub);
    float Nsub = fmaxf(sqrtf(SUB2), MIN_NORM);
    float outv = (2.0f / lam) * atanhf(fminf(Nsub, 1.0f - 1e-5f)) * sub / Nsub;

    outv += ricci * 1e-7f;
    outv = fmaxf(outv, 0.0f);   // relu

    atomicAdd(&sums[(size_t)h * D + lane], outv);
    if (lane == 0) atomicAdd(&cnt[h], 1.0f);
}

// ---------------- per-entity finalize: mean -> l2norm -> residual ----------------

__global__ __launch_bounds__(256) void finalize_hop_kernel(
    const float* __restrict__ sums, const float* __restrict__ cnt,
    const float* __restrict__ prev_res,
    float* __restrict__ ent_out, float* __restrict__ res_out, int n_ent)
{
    int row = blockIdx.x * 4 + (threadIdx.x >> 6);
    if (row >= n_ent) return;
    int lane = threadIdx.x & 63;

    float m = sums[(size_t)row * D + lane] / fmaxf(cnt[row], 1.0f);
    float M2 = wave_sum(m * m);
    float v = m / fmaxf(sqrtf(M2), 1e-12f);   // l2norm

    ent_out[(size_t)row * D + lane] = v;
    res_out[(size_t)row * D + lane] = 0.5f * prev_res[(size_t)row * D + lane] + v;
}

// ---------------- GCN: concat init, COO spmm (atomic), add ----------------

__global__ void concat_init_kernel(const float4* __restrict__ u,
                                   const float4* __restrict__ res,
                                   float4* __restrict__ bufA,
                                   float4* __restrict__ out,
                                   int user4, int total4)
{
    int i = blockIdx.x * blockDim.x + threadIdx.x;
    if (i >= total4) return;
    float4 v = (i < user4) ? u[i] : res[i - user4];
    bufA[i] = v;
    out[i] = v;
}

__global__ __launch_bounds__(256) void spmm_kernel(
    const float* __restrict__ val, const int* __restrict__ row,
    const int* __restrict__ col,
    const float* __restrict__ cur, float* __restrict__ nxt, int nnz)
{
    int e = blockIdx.x * 4 + (threadIdx.x >> 6);
    if (e >= nnz) return;
    int lane = threadIdx.x & 63;
    int r = row[e];
    int c = col[e];
    float v = val[e];
    atomicAdd(&nxt[(size_t)r * D + lane], v * cur[(size_t)c * D + lane]);
}

__global__ void add_kernel(float4* __restrict__ out, const float4* __restrict__ b, int n)
{
    int i = blockIdx.x * blockDim.x + threadIdx.x;
    if (i >= n) return;
    float4 o = out[i];
    float4 a = b[i];
    o.x += a.x; o.y += a.y; o.z += a.z; o.w += a.w;
    out[i] = o;
}

// ---------------- launch ----------------

extern "C" void kernel_launch(void* const* d_in, const int* in_sizes, int n_in,
                              void* d_out, int out_size, void* d_ws, size_t ws_size,
                              hipStream_t stream)
{
    const float* uE      = (const float*)d_in[0];
    const float* eE      = (const float*)d_in[1];
    const float* rE      = (const float*)d_in[2];
    const float* adj_val = (const float*)d_in[3];
    const int*   e_head  = (const int*)d_in[4];
    const int*   e_tail  = (const int*)d_in[5];
    const int*   e_type  = (const int*)d_in[6];
    const int*   a_row   = (const int*)d_in[7];
    const int*   a_col   = (const int*)d_in[8];

    const int n_user  = in_sizes[0] / D;   // 100000
    const int n_ent   = in_sizes[1] / D;   // 200000
    const int nnz     = in_sizes[3];       // 2000000
    const int n_edges = in_sizes[4];       // 500000
    const int n_rows  = out_size / D;      // 150000 (users + items)

    float* ws = (float*)d_ws;
    const size_t entElems = (size_t)n_ent * D;           // 12.8M floats
    float* sums    = ws;                                  // later: GCN bufA
    float* ent1    = ws + entElems;                       // later: GCN bufB
    float* ent_res = ws + 2 * entElems;
    float* cnt     = ws + 3 * entElems;

    float* out = (float*)d_out;

    const int edge_blocks = (n_edges + 3) / 4;
    const int ent_blocks  = (n_ent + 3) / 4;
    const int nnz_blocks  = (nnz + 3) / 4;

    // ---- RGAT hop 1 (input: eEmbeds) ----
    hipMemsetAsync(sums, 0, entElems * sizeof(float), stream);
    hipMemsetAsync(cnt, 0, (size_t)n_ent * sizeof(float), stream);
    rgat_edge_kernel<<<edge_blocks, 256, 0, stream>>>(eE, rE, e_head, e_tail, e_type,
                                                      sums, cnt, n_edges);
    // ent1 = l2norm(mean); ent_res = 0.5*eEmbeds + ent1
    finalize_hop_kernel<<<ent_blocks, 256, 0, stream>>>(sums, cnt, eE, ent1, ent_res, n_ent);

    // ---- RGAT hop 2 (input: ent1) ----
    hipMemsetAsync(sums, 0, entElems * sizeof(float), stream);
    hipMemsetAsync(cnt, 0, (size_t)n_ent * sizeof(float), stream);
    rgat_edge_kernel<<<edge_blocks, 256, 0, stream>>>(ent1, rE, e_head, e_tail, e_type,
                                                      sums, cnt, n_edges);
    // ent_res = 0.5*ent_res + l2norm(mean)   (ent1 overwritten, unused after)
    finalize_hop_kernel<<<ent_blocks, 256, 0, stream>>>(sums, cnt, ent_res, ent1, ent_res, n_ent);

    // ---- GCN ----
    float* bufA = sums;   // reuse (12.8M >= 9.6M floats)
    float* bufB = ent1;

    const int total4 = n_rows * (D / 4);     // 2.4M float4
    const int user4  = n_user * (D / 4);

    // embeds = concat(uEmbeds, ent_res[:n_item]); total(out) = embeds; bufA = embeds
    concat_init_kernel<<<(total4 + 255) / 256, 256, 0, stream>>>(
        (const float4*)uE, (const float4*)ent_res, (float4*)bufA, (float4*)out,
        user4, total4);

    // layer 1: bufB = spmm(adj, bufA); out += bufB
    hipMemsetAsync(bufB, 0, (size_t)n_rows * D * sizeof(float), stream);
    spmm_kernel<<<nnz_blocks, 256, 0, stream>>>(adj_val, a_row, a_col, bufA, bufB, nnz);
    add_kernel<<<(total4 + 255) / 256, 256, 0, stream>>>((float4*)out, (const float4*)bufB, total4);

    // layer 2: bufA = spmm(adj, bufB); out += bufA
    hipMemsetAsync(bufA, 0, (size_t)n_rows * D * sizeof(float), stream);
    spmm_kernel<<<nnz_blocks, 256, 0, stream>>>(adj_val, a_row, a_col, bufB, bufA, nnz);
    add_kernel<<<(total4 + 255) / 256, 256, 0, stream>>>((float4*)out, (const float4*)bufA, total4);
}

// Round 2
// 2088.759 us; speedup vs baseline: 1.1036x; 1.1036x over previous
//
#include <hip/hip_runtime.h>
#include <math.h>

#define D 64
#define MIN_NORM 1e-15f

// ---------------- fast transcendentals (args >= 0) ----------------

__device__ __forceinline__ float fast_tanh_pos(float x) {
    // x >= 0: tanh(x) = (1 - e^-2x) / (1 + e^-2x)
    float t = __expf(-2.0f * x);
    return (1.0f - t) / (1.0f + t);
}

__device__ __forceinline__ float fast_atanh(float x) {
    // x in [0, 1)
    return 0.5f * __logf((1.0f + x) / (1.0f - x));
}

// ---------------- RGAT edge kernel: one wave per edge ----------------
// All Mobius-chain vectors are linear combos of (he, te, re); one 6-way
// interleaved butterfly over the Gram matrix replaces 19 wave reductions.

__global__ __launch_bounds__(256) void rgat_edge_kernel(
    const float* __restrict__ ent, const float* __restrict__ rel,
    const int* __restrict__ head, const int* __restrict__ tail,
    const int* __restrict__ etype,
    float* __restrict__ sums, float* __restrict__ cnt, int n_edges)
{
    int e = blockIdx.x * 4 + (threadIdx.x >> 6);
    if (e >= n_edges) return;
    int lane = threadIdx.x & 63;

    int h = head[e];
    int t = tail[e];
    int r = etype[e] - 1;

    float he = ent[(size_t)h * D + lane];
    float te = ent[(size_t)t * D + lane];
    float re = rel[(size_t)r * D + lane];

    // Gram matrix: 6 independent butterflies, interleaved for ILP
    float v0 = he * he, v1 = te * te, v2 = re * re;
    float v3 = he * te, v4 = he * re, v5 = te * re;
#pragma unroll
    for (int off = 1; off < 64; off <<= 1) {
        v0 += __shfl_xor(v0, off, 64);
        v1 += __shfl_xor(v1, off, 64);
        v2 += __shfl_xor(v2, off, 64);
        v3 += __shfl_xor(v3, off, 64);
        v4 += __shfl_xor(v4, off, 64);
        v5 += __shfl_xor(v5, off, 64);
    }
    float HE2 = v0, TE2 = v1, RE2 = v2, HT = v3, HR = v4, TR = v5;

    // ---- wave-uniform scalar chain ----
    // ricci = l2norm(te+re) * 1e-7
    float S2 = TE2 + 2.0f * TR + RE2;
    float ricci_k = 1e-7f / fmaxf(sqrtf(fmaxf(S2, 0.0f)), 1e-12f);

    // hh = expmap0(he) = a*he
    float Nhe = fmaxf(sqrtf(HE2), MIN_NORM);
    float a = fast_tanh_pos(Nhe) / Nhe;
    float HH2 = a * a * HE2;
    float lam = 2.0f / fmaxf(1.0f - HH2, MIN_NORM);

    // wt = b*te ; wr = c*re  (tangent args of expmap at hh)
    float Nte = fmaxf(sqrtf(TE2), MIN_NORM);
    float b = fast_tanh_pos(0.5f * lam * Nte) / Nte;
    float Nre = fmaxf(sqrtf(RE2), MIN_NORM);
    float c = fast_tanh_pos(0.5f * lam * Nre) / Nre;

    // ht = mobius_add(hh, wt) = p1*he + q1*te
    float y2t = b * b * TE2, xyt = a * b * HT;
    float A1 = 1.0f + 2.0f * xyt + y2t, B1 = 1.0f - HH2;
    float d1 = fmaxf(1.0f + 2.0f * xyt + HH2 * y2t, MIN_NORM);
    float p1 = A1 * a / d1, q1 = B1 * b / d1;
    float HT2 = fmaxf((A1 * A1 * HH2 + 2.0f * A1 * B1 * xyt + B1 * B1 * y2t) / (d1 * d1), 0.0f);

    // hr = mobius_add(hh, wr) = p2*he + q2*re
    float y2r = c * c * RE2, xyr = a * c * HR;
    float A2 = 1.0f + 2.0f * xyr + y2r, B2 = 1.0f - HH2;
    float d2 = fmaxf(1.0f + 2.0f * xyr + HH2 * y2r, MIN_NORM);
    float p2 = A2 * a / d2, q2 = B2 * c / d2;
    float HR2 = fmaxf((A2 * A2 * HH2 + 2.0f * A2 * B2 * xyr + B2 * B2 * y2r) / (d2 * d2), 0.0f);

    // res = mobius_add(ht, hr) = al*he + be*te + ga*re
    float xy3 = p1 * p2 * HE2 + p1 * q2 * HR + q1 * p2 * HT + q1 * q2 * TR;
    float A3 = 1.0f + 2.0f * xy3 + HR2, B3 = 1.0f - HT2;
    float d3 = fmaxf(1.0f + 2.0f * xy3 + HT2 * HR2, MIN_NORM);
    float al = (A3 * p1 + B3 * p2) / d3;
    float be = A3 * q1 / d3;
    float ga = B3 * q2 / d3;
    float R2 = fmaxf((A3 * A3 * HT2 + 2.0f * A3 * B3 * xy3 + B3 * B3 * HR2) / (d3 * d3), 0.0f);

    // project to ball
    float Nr = fmaxf(sqrtf(R2), MIN_NORM);
    const float maxn = 1.0f - 1e-3f;
    if (Nr > maxn) {
        float s = maxn / Nr;
        al *= s; be *= s; ga *= s;
        R2 = maxn * maxn;
    }

    // sub = mobius_add(-hh, res) = sh*he + st*te + sr*re
    float dhr = a * (al * HE2 + be * HT + ga * HR);   // dot(hh, res)
    float xy4 = -dhr;
    float A4 = 1.0f + 2.0f * xy4 + R2, B4 = 1.0f - HH2;
    float d4 = fmaxf(1.0f + 2.0f * xy4 + HH2 * R2, MIN_NORM);
    float sh = (-A4 * a + B4 * al) / d4;
    float st = B4 * be / d4;
    float sr = B4 * ga / d4;
    float SUB2 = fmaxf((A4 * A4 * HH2 + 2.0f * A4 * B4 * xy4 + B4 * B4 * R2) / (d4 * d4), 0.0f);

    float Nsub = fmaxf(sqrtf(SUB2), MIN_NORM);
    float k = (2.0f / lam) * fast_atanh(fminf(Nsub, 1.0f - 1e-5f)) / Nsub;

    // outv = relu(k*sub + ricci*1e-7)
    float outv = k * (sh * he + st * te + sr * re) + ricci_k * (te + re);
    outv = fmaxf(outv, 0.0f);

    atomicAdd(&sums[(size_t)h * D + lane], outv);
    if (lane == 0) atomicAdd(&cnt[h], 1.0f);
}

// ---------------- wave reduce for finalize ----------------

__device__ __forceinline__ float wave_sum(float v) {
    v += __shfl_xor(v, 1, 64);
    v += __shfl_xor(v, 2, 64);
    v += __shfl_xor(v, 4, 64);
    v += __shfl_xor(v, 8, 64);
    v += __shfl_xor(v, 16, 64);
    v += __shfl_xor(v, 32, 64);
    return v;
}

// ---------------- per-entity finalize: mean -> l2norm -> residual ----------------

__global__ __launch_bounds__(256) void finalize_hop_kernel(
    const float* __restrict__ sums, const float* __restrict__ cnt,
    const float* __restrict__ prev_res,
    float* __restrict__ ent_out, float* __restrict__ res_out, int n_ent)
{
    int row = blockIdx.x * 4 + (threadIdx.x >> 6);
    if (row >= n_ent) return;
    int lane = threadIdx.x & 63;

    float m = sums[(size_t)row * D + lane] / fmaxf(cnt[row], 1.0f);
    float M2 = wave_sum(m * m);
    float v = m / fmaxf(sqrtf(M2), 1e-12f);   // l2norm

    ent_out[(size_t)row * D + lane] = v;
    res_out[(size_t)row * D + lane] = 0.5f * prev_res[(size_t)row * D + lane] + v;
}

// ---------------- GCN: concat init, COO spmm (atomic), add ----------------

__global__ void concat_init_kernel(const float4* __restrict__ u,
                                   const float4* __restrict__ res,
                                   float4* __restrict__ bufA,
                                   float4* __restrict__ out,
                                   int user4, int total4)
{
    int i = blockIdx.x * blockDim.x + threadIdx.x;
    if (i >= total4) return;
    float4 v = (i < user4) ? u[i] : res[i - user4];
    bufA[i] = v;
    out[i] = v;
}

__global__ __launch_bounds__(256) void spmm_kernel(
    const float* __restrict__ val, const int* __restrict__ row,
    const int* __restrict__ col,
    const float* __restrict__ cur, float* __restrict__ nxt, int nnz)
{
    int e = blockIdx.x * 4 + (threadIdx.x >> 6);
    if (e >= nnz) return;
    int lane = threadIdx.x & 63;
    int r = row[e];
    int c = col[e];
    float v = val[e];
    atomicAdd(&nxt[(size_t)r * D + lane], v * cur[(size_t)c * D + lane]);
}

__global__ void add_kernel(float4* __restrict__ out, const float4* __restrict__ b, int n)
{
    int i = blockIdx.x * blockDim.x + threadIdx.x;
    if (i >= n) return;
    float4 o = out[i];
    float4 a = b[i];
    o.x += a.x; o.y += a.y; o.z += a.z; o.w += a.w;
    out[i] = o;
}

// ---------------- launch ----------------

extern "C" void kernel_launch(void* const* d_in, const int* in_sizes, int n_in,
                              void* d_out, int out_size, void* d_ws, size_t ws_size,
                              hipStream_t stream)
{
    const float* uE      = (const float*)d_in[0];
    const float* eE      = (const float*)d_in[1];
    const float* rE      = (const float*)d_in[2];
    const float* adj_val = (const float*)d_in[3];
    const int*   e_head  = (const int*)d_in[4];
    const int*   e_tail  = (const int*)d_in[5];
    const int*   e_type  = (const int*)d_in[6];
    const int*   a_row   = (const int*)d_in[7];
    const int*   a_col   = (const int*)d_in[8];

    const int n_user  = in_sizes[0] / D;   // 100000
    const int n_ent   = in_sizes[1] / D;   // 200000
    const int nnz     = in_sizes[3];       // 2000000
    const int n_edges = in_sizes[4];       // 500000
    const int n_rows  = out_size / D;      // 150000 (users + items)

    float* ws = (float*)d_ws;
    const size_t entElems = (size_t)n_ent * D;           // 12.8M floats
    float* sums    = ws;                                  // later: GCN bufA
    float* cnt     = ws + entElems;                       // adjacent -> single memset
    float* ent1    = ws + entElems + n_ent;               // later: GCN bufB
    float* ent_res = ws + 2 * entElems + n_ent;

    float* out = (float*)d_out;

    const int edge_blocks = (n_edges + 3) / 4;
    const int ent_blocks  = (n_ent + 3) / 4;
    const int nnz_blocks  = (nnz + 3) / 4;

    // ---- RGAT hop 1 (input: eEmbeds) ----
    hipMemsetAsync(sums, 0, (entElems + n_ent) * sizeof(float), stream);
    rgat_edge_kernel<<<edge_blocks, 256, 0, stream>>>(eE, rE, e_head, e_tail, e_type,
                                                      sums, cnt, n_edges);
    // ent1 = l2norm(mean); ent_res = 0.5*eEmbeds + ent1
    finalize_hop_kernel<<<ent_blocks, 256, 0, stream>>>(sums, cnt, eE, ent1, ent_res, n_ent);

    // ---- RGAT hop 2 (input: ent1) ----
    hipMemsetAsync(sums, 0, (entElems + n_ent) * sizeof(float), stream);
    rgat_edge_kernel<<<edge_blocks, 256, 0, stream>>>(ent1, rE, e_head, e_tail, e_type,
                                                      sums, cnt, n_edges);
    // ent_res = 0.5*ent_res + l2norm(mean)   (ent1 overwritten, unused after)
    finalize_hop_kernel<<<ent_blocks, 256, 0, stream>>>(sums, cnt, ent_res, ent1, ent_res, n_ent);

    // ---- GCN ----
    float* bufA = sums;   // reuse (12.8M >= 9.6M floats)
    float* bufB = ent1;

    const int total4 = n_rows * (D / 4);     // 2.4M float4
    const int user4  = n_user * (D / 4);

    // embeds = concat(uEmbeds, ent_res[:n_item]); total(out) = embeds; bufA = embeds
    concat_init_kernel<<<(total4 + 255) / 256, 256, 0, stream>>>(
        (const float4*)uE, (const float4*)ent_res, (float4*)bufA, (float4*)out,
        user4, total4);

    // layer 1: bufB = spmm(adj, bufA); out += bufB
    hipMemsetAsync(bufB, 0, (size_t)n_rows * D * sizeof(float), stream);
    spmm_kernel<<<nnz_blocks, 256, 0, stream>>>(adj_val, a_row, a_col, bufA, bufB, nnz);
    add_kernel<<<(total4 + 255) / 256, 256, 0, stream>>>((float4*)out, (const float4*)bufB, total4);

    // layer 2: bufA = spmm(adj, bufB); out += bufA
    hipMemsetAsync(bufA, 0, (size_t)n_rows * D * sizeof(float), stream);
    spmm_kernel<<<nnz_blocks, 256, 0, stream>>>(adj_val, a_row, a_col, bufB, bufA, nnz);
    add_kernel<<<(total4 + 255) / 256, 256, 0, stream>>>((float4*)out, (const float4*)bufA, total4);
}